// Round 1
// baseline (250.438 us; speedup 1.0000x reference)
//
#include <hip/hip_runtime.h>
#include <stdint.h>

#define N_BATCH 32
#define B_OBJ   36
#define D_DIM   2048
#define Q_DIM   1024

typedef __bf16 bf16x8 __attribute__((ext_vector_type(8)));
typedef float  f32x4  __attribute__((ext_vector_type(4)));

__device__ __forceinline__ uint16_t f2bf(float f) {
    uint32_t u = __builtin_bit_cast(uint32_t, f);
    uint32_t r = (u + 0x7FFFu + ((u >> 16) & 1u)) >> 16;   // RNE
    return (uint16_t)r;
}

// ---- transpose + fp32->bf16: Wt[n*K + k] = bf16(W[k*N + n]) ----
__global__ void transpose_to_bf16(const float* __restrict__ W,
                                  uint16_t* __restrict__ Wt,
                                  int K, int N) {
    __shared__ float tile[32][33];
    int n0 = blockIdx.x * 32;
    int k0 = blockIdx.y * 32;
    int tx = threadIdx.x;   // 0..31
    int ty = threadIdx.y;   // 0..7
#pragma unroll
    for (int r = 0; r < 4; ++r)
        tile[ty + 8 * r][tx] = W[(size_t)(k0 + ty + 8 * r) * N + n0 + tx];
    __syncthreads();
#pragma unroll
    for (int r = 0; r < 4; ++r)
        Wt[(size_t)(n0 + ty + 8 * r) * K + k0 + tx] = f2bf(tile[tx][ty + 8 * r]);
}

// ---- fp32 -> bf16 copy ----
__global__ void convert_bf16(const float* __restrict__ in,
                             uint16_t* __restrict__ out, int n) {
    int i = blockIdx.x * 256 + threadIdx.x;
    if (i < n) out[i] = f2bf(in[i]);
}

// ---- u[n,i,d] = bf16(v[n,i,d] * qe[n,d]) ----
__global__ void make_u(const float* __restrict__ v,
                       const float* __restrict__ qe,
                       uint16_t* __restrict__ u) {
    int idx = blockIdx.x * 256 + threadIdx.x;            // float4 group id
    const int total = (N_BATCH * B_OBJ * D_DIM) / 4;
    if (idx >= total) return;
    int d4 = idx % (D_DIM / 4);
    int nb = idx / ((B_OBJ * D_DIM) / 4);
    float4 vv = ((const float4*)v)[idx];
    float4 qq = ((const float4*)qe)[(size_t)nb * (D_DIM / 4) + d4];
    ushort4 o;
    o.x = f2bf(vv.x * qq.x);
    o.y = f2bf(vv.y * qq.y);
    o.z = f2bf(vv.z * qq.z);
    o.w = f2bf(vv.w * qq.w);
    ((ushort4*)u)[idx] = o;
}

// ---- x[n,i,d] = bf16( sum_j relu(y[n,i,d] + y[n,j,d] + b1[d]) ) ----
__global__ void pairsum(const float* __restrict__ y,
                        const float* __restrict__ b1,
                        uint16_t* __restrict__ x) {
    int n = blockIdx.y;
    int d = blockIdx.x * 256 + threadIdx.x;
    const float* yb = y + (size_t)n * B_OBJ * D_DIM + d;
    float z[B_OBJ];
#pragma unroll
    for (int r = 0; r < B_OBJ; ++r) z[r] = yb[(size_t)r * D_DIM];
    float b = b1[d];
    uint16_t* xb = x + (size_t)n * B_OBJ * D_DIM + d;
#pragma unroll
    for (int i = 0; i < B_OBJ; ++i) {
        float zi = z[i] + b;
        float s = 0.f;
#pragma unroll
        for (int j = 0; j < B_OBJ; ++j)
            s += fmaxf(zi + z[j], 0.f);
        xb[(size_t)i * D_DIM] = f2bf(s);
    }
}

// ---- C(MxN fp32) = A(MxK bf16) * B, with B given as Bt (NxK bf16) ----
// 128x128 tile / block, 4 waves, each wave 64x64 via 4x4 grid of 16x16x32 MFMA.
#define BM 128
#define BN 128
#define BK 32

__global__ __launch_bounds__(256) void gemm_bf16(
    const uint16_t* __restrict__ A,
    const uint16_t* __restrict__ Bt,
    const float* __restrict__ bias,   // len N or nullptr
    float* __restrict__ C,
    int M, int Nn, int K, int do_relu) {
    __shared__ __align__(16) __bf16 As[BM * BK];
    __shared__ __align__(16) __bf16 Bs[BN * BK];
    int t    = threadIdx.x;
    int lane = t & 63;
    int wave = t >> 6;
    int l15  = lane & 15;
    int quad = lane >> 4;
    int wr = wave >> 1, wc = wave & 1;
    int m0 = blockIdx.y * BM;
    int n0 = blockIdx.x * BN;

    f32x4 acc[4][4] = {};

    // staging: 256 threads x (2 A-chunks + 2 B-chunks) of 16B each
    int rowA0 = t >> 2;                  // 0..63
    int rowA1 = rowA0 + 64;              // 64..127
    int kk    = (t & 3) * 8;             // 0,8,16,24

    for (int k0 = 0; k0 < K; k0 += BK) {
        __syncthreads();
        int gr0 = m0 + rowA0; if (gr0 >= M) gr0 = M - 1;
        int gr1 = m0 + rowA1; if (gr1 >= M) gr1 = M - 1;
        *(uint4*)(&As[rowA0 * BK + kk]) = *(const uint4*)(&A[(size_t)gr0 * K + k0 + kk]);
        *(uint4*)(&As[rowA1 * BK + kk]) = *(const uint4*)(&A[(size_t)gr1 * K + k0 + kk]);
        *(uint4*)(&Bs[rowA0 * BK + kk]) = *(const uint4*)(&Bt[(size_t)(n0 + rowA0) * K + k0 + kk]);
        *(uint4*)(&Bs[rowA1 * BK + kk]) = *(const uint4*)(&Bt[(size_t)(n0 + rowA1) * K + k0 + kk]);
        __syncthreads();

        bf16x8 af[4], bfr[4];
#pragma unroll
        for (int i = 0; i < 4; ++i)
            af[i] = *(const bf16x8*)(&As[(wr * 64 + i * 16 + l15) * BK + quad * 8]);
#pragma unroll
        for (int j = 0; j < 4; ++j)
            bfr[j] = *(const bf16x8*)(&Bs[(wc * 64 + j * 16 + l15) * BK + quad * 8]);
#pragma unroll
        for (int i = 0; i < 4; ++i)
#pragma unroll
            for (int j = 0; j < 4; ++j)
                acc[i][j] = __builtin_amdgcn_mfma_f32_16x16x32_bf16(af[i], bfr[j], acc[i][j], 0, 0, 0);
    }

#pragma unroll
    for (int i = 0; i < 4; ++i) {
        int mrow = m0 + wr * 64 + i * 16 + quad * 4;
#pragma unroll
        for (int j = 0; j < 4; ++j) {
            int ncol = n0 + wc * 64 + j * 16 + l15;
            float bs = bias ? bias[ncol] : 0.f;
#pragma unroll
            for (int r = 0; r < 4; ++r) {
                int m = mrow + r;
                if (m < M) {
                    float val = acc[i][j][r] + bs;
                    if (do_relu) val = fmaxf(val, 0.f);
                    C[(size_t)m * Nn + ncol] = val;
                }
            }
        }
    }
}

extern "C" void kernel_launch(void* const* d_in, const int* in_sizes, int n_in,
                              void* d_out, int out_size, void* d_ws, size_t ws_size,
                              hipStream_t stream) {
    const float* v  = (const float*)d_in[0];
    const float* q  = (const float*)d_in[1];
    const float* W1 = (const float*)d_in[2];
    const float* b1 = (const float*)d_in[3];
    const float* W2 = (const float*)d_in[4];
    const float* b2 = (const float*)d_in[5];
    const float* W3 = (const float*)d_in[6];
    const float* b3 = (const float*)d_in[7];
    float* out = (float*)d_out;

    char* ws = (char*)d_ws;
    uint16_t* W1t = (uint16_t*)(ws + 0);          // 2048*2048 bf16 = 8 MiB
    uint16_t* W2t = (uint16_t*)(ws + 8388608);    // 8 MiB
    uint16_t* W3t = (uint16_t*)(ws + 16777216);   // 2048*1024 bf16 = 4 MiB
    uint16_t* qb  = (uint16_t*)(ws + 20971520);   // 32*1024 bf16
    float*    qe  = (float*)   (ws + 21037056);   // 32*2048 f32
    uint16_t* u   = (uint16_t*)(ws + 21299200);   // 1152*2048 bf16
    float*    y   = (float*)   (ws + 26017792);   // 1152*2048 f32 (ends 35454976)
    // x reuses the W3t/qb/qe/u-prefix region (all dead by the time pairsum runs)
    uint16_t* x   = (uint16_t*)(ws + 16777216);   // 1152*2048 bf16

    // weight prep
    transpose_to_bf16<<<dim3(64, 64), dim3(32, 8), 0, stream>>>(W1, W1t, 2048, 2048);
    transpose_to_bf16<<<dim3(64, 64), dim3(32, 8), 0, stream>>>(W2, W2t, 2048, 2048);
    transpose_to_bf16<<<dim3(64, 32), dim3(32, 8), 0, stream>>>(W3, W3t, 1024, 2048);
    convert_bf16<<<128, 256, 0, stream>>>(q, qb, N_BATCH * Q_DIM);

    // qe = relu(q @ W3 + b3)   (32 x 2048)
    gemm_bf16<<<dim3(16, 1), 256, 0, stream>>>(qb, W3t, b3, qe, N_BATCH, D_DIM, Q_DIM, 1);

    // u = bf16(v * qe)
    make_u<<<(N_BATCH * B_OBJ * D_DIM / 4 + 255) / 256, 256, 0, stream>>>(v, qe, u);

    // y = u @ W1   (1152 x 2048, no bias/relu)
    gemm_bf16<<<dim3(16, 9), 256, 0, stream>>>(u, W1t, nullptr, y, N_BATCH * B_OBJ, D_DIM, D_DIM, 0);

    // x = pair-sum relu
    pairsum<<<dim3(D_DIM / 256, N_BATCH), 256, 0, stream>>>(y, b1, x);

    // out = relu(x @ W2 + b2)
    gemm_bf16<<<dim3(16, 9), 256, 0, stream>>>(x, W2t, b2, out, N_BATCH * B_OBJ, D_DIM, D_DIM, 1);
}

// Round 2
// 208.601 us; speedup vs baseline: 1.2006x; 1.2006x over previous
//
#include <hip/hip_runtime.h>
#include <stdint.h>

#define N_BATCH 32
#define B_OBJ   36
#define D_DIM   2048
#define Q_DIM   1024

typedef __bf16 bf16x8 __attribute__((ext_vector_type(8)));
typedef float  f32x4  __attribute__((ext_vector_type(4)));

__device__ __forceinline__ uint16_t f2bf(float f) {
    uint32_t u = __builtin_bit_cast(uint32_t, f);
    uint32_t r = (u + 0x7FFFu + ((u >> 16) & 1u)) >> 16;   // RNE
    return (uint16_t)r;
}

__device__ __forceinline__ void gld_lds16(const void* g, void* l) {
    __builtin_amdgcn_global_load_lds(
        (const __attribute__((address_space(1))) uint32_t*)g,
        (__attribute__((address_space(3))) uint32_t*)l, 16, 0, 0);
}

// ---- fused transpose + fp32->bf16 for W1, W2, W3 (all N=2048 cols) ----
__global__ void transpose_all(const float* __restrict__ W1,
                              const float* __restrict__ W2,
                              const float* __restrict__ W3,
                              uint16_t* __restrict__ W1t,
                              uint16_t* __restrict__ W2t,
                              uint16_t* __restrict__ W3t) {
    __shared__ float tile[32][33];
    int gy = blockIdx.y;
    const float* W; uint16_t* Wt; int K, k0;
    if (gy < 64)       { W = W1; Wt = W1t; K = 2048; k0 = gy * 32; }
    else if (gy < 128) { W = W2; Wt = W2t; K = 2048; k0 = (gy - 64) * 32; }
    else               { W = W3; Wt = W3t; K = 1024; k0 = (gy - 128) * 32; }
    int n0 = blockIdx.x * 32;
    int tx = threadIdx.x, ty = threadIdx.y;
#pragma unroll
    for (int r = 0; r < 4; ++r)
        tile[ty + 8 * r][tx] = W[(size_t)(k0 + ty + 8 * r) * 2048 + n0 + tx];
    __syncthreads();
#pragma unroll
    for (int r = 0; r < 4; ++r)
        Wt[(size_t)(n0 + ty + 8 * r) * K + k0 + tx] = f2bf(tile[tx][ty + 8 * r]);
}

// ---- qe GEMM: qpart[z] = q @ W3 over K-chunk z (M=32, N=2048, split-K=4) ----
__global__ __launch_bounds__(256) void qk_gemm(
    const float* __restrict__ q,       // 32 x 1024 fp32
    const uint16_t* __restrict__ W3t,  // 2048 x 1024 bf16 (n-major)
    float* __restrict__ qpart) {       // 4 x 32 x 2048 fp32
    __shared__ __align__(16) uint16_t As[32][32];
    __shared__ __align__(16) uint16_t Bs[128][32];
    int t = threadIdx.x, lane = t & 63, wave = t >> 6;
    int l15 = lane & 15, quad = lane >> 4;
    int n0 = blockIdx.x * 128;
    int kbase = blockIdx.y * 256;
    f32x4 acc[2][2] = {};
    int ar = t >> 3, ac = (t & 7) * 4;     // A staging: 32 rows x 32 k fp32
    int br = t >> 2, bk = (t & 3) * 8;     // B staging

    for (int k0 = 0; k0 < 256; k0 += 32) {
        __syncthreads();
        float4 av = *(const float4*)&q[(size_t)ar * Q_DIM + kbase + k0 + ac];
        ushort4 a4;
        a4.x = f2bf(av.x); a4.y = f2bf(av.y); a4.z = f2bf(av.z); a4.w = f2bf(av.w);
        *(ushort4*)&As[ar][ac] = a4;
        *(uint4*)&Bs[br][bk]      = *(const uint4*)&W3t[(size_t)(n0 + br) * Q_DIM + kbase + k0 + bk];
        *(uint4*)&Bs[br + 64][bk] = *(const uint4*)&W3t[(size_t)(n0 + br + 64) * Q_DIM + kbase + k0 + bk];
        __syncthreads();
        bf16x8 af[2], bfr[2];
        af[0]  = *(const bf16x8*)&As[l15][quad * 8];
        af[1]  = *(const bf16x8*)&As[16 + l15][quad * 8];
        bfr[0] = *(const bf16x8*)&Bs[wave * 32 + l15][quad * 8];
        bfr[1] = *(const bf16x8*)&Bs[wave * 32 + 16 + l15][quad * 8];
#pragma unroll
        for (int i = 0; i < 2; ++i)
#pragma unroll
            for (int j = 0; j < 2; ++j)
                acc[i][j] = __builtin_amdgcn_mfma_f32_16x16x32_bf16(af[i], bfr[j], acc[i][j], 0, 0, 0);
    }
    float* dst = qpart + (size_t)blockIdx.y * 32 * D_DIM;
#pragma unroll
    for (int i = 0; i < 2; ++i)
#pragma unroll
        for (int j = 0; j < 2; ++j) {
            int n = n0 + wave * 32 + j * 16 + l15;
#pragma unroll
            for (int r = 0; r < 4; ++r) {
                int m = i * 16 + quad * 4 + r;
                dst[(size_t)m * D_DIM + n] = acc[i][j][r];
            }
        }
}

// ---- qe = relu(sum_z qpart + b3) ----
__global__ void qe_reduce(const float* __restrict__ qpart,
                          const float* __restrict__ b3,
                          float* __restrict__ qe) {
    int i = blockIdx.x * 256 + threadIdx.x;     // float4 id, 16384 total
    const float4* p = (const float4*)qpart;
    float4 s = p[i];
    float4 s1 = p[16384 + i], s2 = p[32768 + i], s3 = p[49152 + i];
    float4 b = ((const float4*)b3)[i & 511];
    float4 o;
    o.x = fmaxf(s.x + s1.x + s2.x + s3.x + b.x, 0.f);
    o.y = fmaxf(s.y + s1.y + s2.y + s3.y + b.y, 0.f);
    o.z = fmaxf(s.z + s1.z + s2.z + s3.z + b.z, 0.f);
    o.w = fmaxf(s.w + s1.w + s2.w + s3.w + b.w, 0.f);
    ((float4*)qe)[i] = o;
}

// ---- u[n,i,d] = bf16(v[n,i,d] * qe[n,d]) ----
__global__ void make_u(const float* __restrict__ v,
                       const float* __restrict__ qe,
                       uint16_t* __restrict__ u) {
    int idx = blockIdx.x * 256 + threadIdx.x;
    const int total = (N_BATCH * B_OBJ * D_DIM) / 4;
    if (idx >= total) return;
    int d4 = idx % (D_DIM / 4);
    int nb = idx / ((B_OBJ * D_DIM) / 4);
    float4 vv = ((const float4*)v)[idx];
    float4 qq = ((const float4*)qe)[(size_t)nb * (D_DIM / 4) + d4];
    ushort4 o;
    o.x = f2bf(vv.x * qq.x);
    o.y = f2bf(vv.y * qq.y);
    o.z = f2bf(vv.z * qq.z);
    o.w = f2bf(vv.w * qq.w);
    ((ushort4*)u)[idx] = o;
}

// ---- x[n,i,d] = bf16( sum_j relu(y[n,i,d] + y[n,j,d] + b1[d]) ) ----
__global__ void pairsum(const float* __restrict__ y,
                        const float* __restrict__ b1,
                        uint16_t* __restrict__ x) {
    int n = blockIdx.y;
    int d = blockIdx.x * 256 + threadIdx.x;
    const float* yb = y + (size_t)n * B_OBJ * D_DIM + d;
    float z[B_OBJ];
#pragma unroll
    for (int r = 0; r < B_OBJ; ++r) z[r] = yb[(size_t)r * D_DIM];
    float b = b1[d];
    uint16_t* xb = x + (size_t)n * B_OBJ * D_DIM + d;
#pragma unroll
    for (int i = 0; i < B_OBJ; ++i) {
        float zi = z[i] + b;
        float s = 0.f;
#pragma unroll
        for (int j = 0; j < B_OBJ; ++j)
            s += fmaxf(zi + z[j], 0.f);
        xb[(size_t)i * D_DIM] = f2bf(s);
    }
}

// ---- main GEMM: C(MxN f32) = A(MxK bf16) @ Bt(NxK bf16)^T, M % 128 == 0 ----
// 128x128 tile, BK=64 (two 32-wide halves), global_load_lds staging (m97-style).
#define BM 128
#define BN 128
#define BK 64

__global__ __launch_bounds__(256) void gemm_bf16(
    const uint16_t* __restrict__ A,
    const uint16_t* __restrict__ Bt,
    const float* __restrict__ bias,
    float* __restrict__ C,
    int M, int Nn, int K, int do_relu) {
    // layout: [half][row][32] so fragment reads keep m97's proven 64B-row pattern
    __shared__ __align__(16) uint16_t As[2][BM][32];
    __shared__ __align__(16) uint16_t Bs[2][BN][32];
    int t = threadIdx.x, lane = t & 63, wave = t >> 6;
    int l15 = lane & 15, quad = lane >> 4;
    int wr = wave >> 1, wc = wave & 1;
    int m0 = blockIdx.y * BM, n0 = blockIdx.x * BN;

    // 16 A-regions + 16 B-regions of 1 KiB; wave w stages regions w*4..w*4+3.
    // region r: half h=r>>3, row (r&7)*16 + lane/4, k = h*32 + (lane&3)*8
    const uint16_t* aG[4]; const uint16_t* bG[4];
    uint16_t* aL[4]; uint16_t* bL[4];
#pragma unroll
    for (int c = 0; c < 4; ++c) {
        int r = wave * 4 + c;
        int h = r >> 3;
        int row = (r & 7) * 16 + (lane >> 2);
        int kk = h * 32 + (lane & 3) * 8;
        aG[c] = A  + (size_t)(m0 + row) * K + kk;
        bG[c] = Bt + (size_t)(n0 + row) * K + kk;
        aL[c] = &As[0][0][0] + r * 512;   // wave-uniform region base (HW adds lane*16)
        bL[c] = &Bs[0][0][0] + r * 512;
    }

    f32x4 acc[4][4] = {};

    for (int k0 = 0; k0 < K; k0 += BK) {
        __syncthreads();
#pragma unroll
        for (int c = 0; c < 4; ++c) {
            gld_lds16(aG[c] + k0, aL[c]);
            gld_lds16(bG[c] + k0, bL[c]);
        }
        __syncthreads();
#pragma unroll
        for (int s = 0; s < 2; ++s) {
            bf16x8 af[4], bfr[4];
#pragma unroll
            for (int i = 0; i < 4; ++i)
                af[i] = *(const bf16x8*)&As[s][wr * 64 + i * 16 + l15][quad * 8];
#pragma unroll
            for (int j = 0; j < 4; ++j)
                bfr[j] = *(const bf16x8*)&Bs[s][wc * 64 + j * 16 + l15][quad * 8];
#pragma unroll
            for (int i = 0; i < 4; ++i)
#pragma unroll
                for (int j = 0; j < 4; ++j)
                    acc[i][j] = __builtin_amdgcn_mfma_f32_16x16x32_bf16(af[i], bfr[j], acc[i][j], 0, 0, 0);
        }
    }

#pragma unroll
    for (int i = 0; i < 4; ++i) {
        int mrow = m0 + wr * 64 + i * 16 + quad * 4;
#pragma unroll
        for (int j = 0; j < 4; ++j) {
            int ncol = n0 + wc * 64 + j * 16 + l15;
            float bs = bias ? bias[ncol] : 0.f;
#pragma unroll
            for (int r = 0; r < 4; ++r) {
                float val = acc[i][j][r] + bs;
                if (do_relu) val = fmaxf(val, 0.f);
                C[(size_t)(mrow + r) * Nn + ncol] = val;
            }
        }
    }
}

extern "C" void kernel_launch(void* const* d_in, const int* in_sizes, int n_in,
                              void* d_out, int out_size, void* d_ws, size_t ws_size,
                              hipStream_t stream) {
    const float* v  = (const float*)d_in[0];
    const float* q  = (const float*)d_in[1];
    const float* W1 = (const float*)d_in[2];
    const float* b1 = (const float*)d_in[3];
    const float* W2 = (const float*)d_in[4];
    const float* b2 = (const float*)d_in[5];
    const float* W3 = (const float*)d_in[6];
    const float* b3 = (const float*)d_in[7];
    float* out = (float*)d_out;

    char* ws = (char*)d_ws;
    uint16_t* W1t   = (uint16_t*)(ws + 0);           // 8 MiB, live until gemm1
    uint16_t* W2t   = (uint16_t*)(ws + 8388608);     // 8 MiB, live until gemm2
    uint16_t* W3t   = (uint16_t*)(ws + 16777216);    // 4 MiB, dead after qk_gemm
    uint16_t* u     = (uint16_t*)(ws + 16777216);    // 4.5 MiB, overlays dead W3t
    uint16_t* x     = (uint16_t*)(ws + 16777216);    // overlays dead u
    float*    qpart = (float*)   (ws + 21495808);    // 1 MiB
    float*    qe    = (float*)   (ws + 22544384);    // 256 KiB
    float*    y     = (float*)   (ws + 22806528);    // 9 MiB (ends 32243712)

    transpose_all<<<dim3(64, 160), dim3(32, 8), 0, stream>>>(W1, W2, W3, W1t, W2t, W3t);

    qk_gemm<<<dim3(16, 4), 256, 0, stream>>>(q, W3t, qpart);
    qe_reduce<<<64, 256, 0, stream>>>(qpart, b3, qe);

    make_u<<<(N_BATCH * B_OBJ * D_DIM / 4 + 255) / 256, 256, 0, stream>>>(v, qe, u);

    gemm_bf16<<<dim3(16, 9), 256, 0, stream>>>(u, W1t, nullptr, y,
                                               N_BATCH * B_OBJ, D_DIM, D_DIM, 0);

    pairsum<<<dim3(D_DIM / 256, N_BATCH), 256, 0, stream>>>(y, b1, x);

    gemm_bf16<<<dim3(16, 9), 256, 0, stream>>>(x, W2t, b2, out,
                                               N_BATCH * B_OBJ, D_DIM, D_DIM, 1);
}

// Round 3
// 178.966 us; speedup vs baseline: 1.3994x; 1.1656x over previous
//
#include <hip/hip_runtime.h>
#include <stdint.h>

#define N_BATCH 32
#define B_OBJ   36
#define D_DIM   2048
#define Q_DIM   1024

typedef __bf16 bf16x8 __attribute__((ext_vector_type(8)));
typedef float  f32x4  __attribute__((ext_vector_type(4)));

__device__ __forceinline__ uint16_t f2bf(float f) {
    uint32_t u = __builtin_bit_cast(uint32_t, f);
    uint32_t r = (u + 0x7FFFu + ((u >> 16) & 1u)) >> 16;   // RNE
    return (uint16_t)r;
}

__device__ __forceinline__ void gld_lds16(const void* g, void* l) {
    __builtin_amdgcn_global_load_lds(
        (const __attribute__((address_space(1))) uint32_t*)g,
        (__attribute__((address_space(3))) uint32_t*)l, 16, 0, 0);
}

// ---- transpose + fp32->bf16, 64x64 tiles, vectorized ----
__global__ __launch_bounds__(256) void transpose_all(
    const float* __restrict__ W1, const float* __restrict__ W2,
    const float* __restrict__ W3,
    uint16_t* __restrict__ W1t, uint16_t* __restrict__ W2t,
    uint16_t* __restrict__ W3t) {
    __shared__ float tile[64][65];
    int gy = blockIdx.y;
    const float* W; uint16_t* Wt; int K, k0;
    if (gy < 32)      { W = W1; Wt = W1t; K = 2048; k0 = gy * 64; }
    else if (gy < 64) { W = W2; Wt = W2t; K = 2048; k0 = (gy - 32) * 64; }
    else              { W = W3; Wt = W3t; K = 1024; k0 = (gy - 64) * 64; }
    int n0 = blockIdx.x * 64;
    int t = threadIdx.x;
    {
        int r = t >> 4, c = (t & 15) * 4;
#pragma unroll
        for (int p = 0; p < 4; ++p)
            *(float4*)&tile[r + p * 16][c] =
                *(const float4*)&W[(size_t)(k0 + r + p * 16) * 2048 + n0 + c];
    }
    __syncthreads();
    {
        int n = t >> 2, kb = (t & 3) * 16;
#pragma unroll
        for (int g4 = 0; g4 < 4; ++g4) {
            int k = kb + g4 * 4;
            ushort4 o;
            o.x = f2bf(tile[k][n]);     o.y = f2bf(tile[k + 1][n]);
            o.z = f2bf(tile[k + 2][n]); o.w = f2bf(tile[k + 3][n]);
            *(ushort4*)&Wt[(size_t)(n0 + n) * K + k0 + k] = o;
        }
    }
}

// ---- qe GEMM: qpart[z] = q @ W3 over K-chunk z (M=32, N=2048, split-K=4) ----
__global__ __launch_bounds__(256) void qk_gemm(
    const float* __restrict__ q,
    const uint16_t* __restrict__ W3t,
    float* __restrict__ qpart) {
    __shared__ __align__(16) uint16_t As[32][32];
    __shared__ __align__(16) uint16_t Bs[128][32];
    int t = threadIdx.x, lane = t & 63, wave = t >> 6;
    int l15 = lane & 15, quad = lane >> 4;
    int n0 = blockIdx.x * 128;
    int kbase = blockIdx.y * 256;
    f32x4 acc[2][2] = {};
    int ar = t >> 3, ac = (t & 7) * 4;
    int br = t >> 2, bk = (t & 3) * 8;

    for (int k0 = 0; k0 < 256; k0 += 32) {
        __syncthreads();
        float4 av = *(const float4*)&q[(size_t)ar * Q_DIM + kbase + k0 + ac];
        ushort4 a4;
        a4.x = f2bf(av.x); a4.y = f2bf(av.y); a4.z = f2bf(av.z); a4.w = f2bf(av.w);
        *(ushort4*)&As[ar][ac] = a4;
        *(uint4*)&Bs[br][bk]      = *(const uint4*)&W3t[(size_t)(n0 + br) * Q_DIM + kbase + k0 + bk];
        *(uint4*)&Bs[br + 64][bk] = *(const uint4*)&W3t[(size_t)(n0 + br + 64) * Q_DIM + kbase + k0 + bk];
        __syncthreads();
        bf16x8 af[2], bfr[2];
        af[0]  = *(const bf16x8*)&As[l15][quad * 8];
        af[1]  = *(const bf16x8*)&As[16 + l15][quad * 8];
        bfr[0] = *(const bf16x8*)&Bs[wave * 32 + l15][quad * 8];
        bfr[1] = *(const bf16x8*)&Bs[wave * 32 + 16 + l15][quad * 8];
#pragma unroll
        for (int i = 0; i < 2; ++i)
#pragma unroll
            for (int j = 0; j < 2; ++j)
                acc[i][j] = __builtin_amdgcn_mfma_f32_16x16x32_bf16(af[i], bfr[j], acc[i][j], 0, 0, 0);
    }
    float* dst = qpart + (size_t)blockIdx.y * 32 * D_DIM;
#pragma unroll
    for (int i = 0; i < 2; ++i)
#pragma unroll
        for (int j = 0; j < 2; ++j) {
            int n = n0 + wave * 32 + j * 16 + l15;
#pragma unroll
            for (int r = 0; r < 4; ++r)
                dst[(size_t)(i * 16 + quad * 4 + r) * D_DIM + n] = acc[i][j][r];
        }
}

// ---- qe = relu(sum_z qpart + b3) ----
__global__ void qe_reduce(const float* __restrict__ qpart,
                          const float* __restrict__ b3,
                          float* __restrict__ qe) {
    int i = blockIdx.x * 256 + threadIdx.x;
    const float4* p = (const float4*)qpart;
    float4 s = p[i];
    float4 s1 = p[16384 + i], s2 = p[32768 + i], s3 = p[49152 + i];
    float4 b = ((const float4*)b3)[i & 511];
    float4 o;
    o.x = fmaxf(s.x + s1.x + s2.x + s3.x + b.x, 0.f);
    o.y = fmaxf(s.y + s1.y + s2.y + s3.y + b.y, 0.f);
    o.z = fmaxf(s.z + s1.z + s2.z + s3.z + b.z, 0.f);
    o.w = fmaxf(s.w + s1.w + s2.w + s3.w + b.w, 0.f);
    ((float4*)qe)[i] = o;
}

// ---- u[n,i,d] = bf16(v[n,i,d] * qe[n,d]) ----
__global__ void make_u(const float* __restrict__ v,
                       const float* __restrict__ qe,
                       uint16_t* __restrict__ u) {
    int idx = blockIdx.x * 256 + threadIdx.x;
    const int total = (N_BATCH * B_OBJ * D_DIM) / 4;
    if (idx >= total) return;
    int d4 = idx % (D_DIM / 4);
    int nb = idx / ((B_OBJ * D_DIM) / 4);
    float4 vv = ((const float4*)v)[idx];
    float4 qq = ((const float4*)qe)[(size_t)nb * (D_DIM / 4) + d4];
    ushort4 o;
    o.x = f2bf(vv.x * qq.x);
    o.y = f2bf(vv.y * qq.y);
    o.z = f2bf(vv.z * qq.z);
    o.w = f2bf(vv.w * qq.w);
    ((ushort4*)u)[idx] = o;
}

// ---- per-batch GEMM: tile M=48(36 real) x N=128, K=2048, BK=64 ----
// mode 0: pairsum epilogue -> x (bf16). mode 1: relu(+bias) -> out (f32).
__global__ __launch_bounds__(256) void gemm_batch(
    const uint16_t* __restrict__ A,    // 1152 x 2048 bf16
    const uint16_t* __restrict__ Bt,   // 2048 x 2048 bf16 (n-major)
    const float* __restrict__ bias,
    void* __restrict__ Cv,
    int mode) {
    // smem union: K-loop uses As[2][48][32]+Bs[2][128][32] = 22528 B;
    // epilogue uses ytile[48][132] f32 = 25344 B.
    __shared__ __align__(16) float smemf[6336];
    uint16_t* As = (uint16_t*)smemf;       // 3072 u16
    uint16_t* Bs = As + 3072;              // 8192 u16
    float* yt = smemf;

    int t = threadIdx.x, lane = t & 63, wave = t >> 6;
    int l15 = lane & 15, quad = lane >> 4;
    int nb = blockIdx.y;
    int n0 = blockIdx.x * 128;
    const uint16_t* Ab = A + (size_t)nb * B_OBJ * D_DIM;

    // 22 staging regions of 1KB: 0..5 = A (h=r/3,g=r%3), 6..21 = B (h,g of rb=r-6)
    const uint16_t* gp[6]; uint16_t* lp[6];
#pragma unroll
    for (int c = 0; c < 6; ++c) {
        int r = wave + 4 * c;
        int rr = (r < 22) ? r : 0;
        if (rr < 6) {
            int h = rr / 3, g = rr % 3;
            int row = g * 16 + (lane >> 2), kk = h * 32 + (lane & 3) * 8;
            gp[c] = Ab + (size_t)row * D_DIM + kk;
            lp[c] = As + h * 1536 + g * 512;
        } else {
            int rb = rr - 6, h = rb >> 3, g = rb & 7;
            int row = g * 16 + (lane >> 2), kk = h * 32 + (lane & 3) * 8;
            gp[c] = Bt + (size_t)(n0 + row) * D_DIM + kk;
            lp[c] = Bs + h * 4096 + g * 512;
        }
    }

    f32x4 acc[3][2] = {};

    for (int k0 = 0; k0 < D_DIM; k0 += 64) {
        __syncthreads();
#pragma unroll
        for (int c = 0; c < 6; ++c)
            if (wave + 4 * c < 22) gld_lds16(gp[c] + k0, lp[c]);
        __syncthreads();
#pragma unroll
        for (int s = 0; s < 2; ++s) {
            bf16x8 af[3], bfr[2];
#pragma unroll
            for (int i = 0; i < 3; ++i)
                af[i] = *(const bf16x8*)(As + s * 1536 + (i * 16 + l15) * 32 + quad * 8);
#pragma unroll
            for (int j = 0; j < 2; ++j)
                bfr[j] = *(const bf16x8*)(Bs + s * 4096 + (wave * 32 + j * 16 + l15) * 32 + quad * 8);
#pragma unroll
            for (int i = 0; i < 3; ++i)
#pragma unroll
                for (int j = 0; j < 2; ++j)
                    acc[i][j] = __builtin_amdgcn_mfma_f32_16x16x32_bf16(af[i], bfr[j], acc[i][j], 0, 0, 0);
        }
    }

    if (mode == 0) {
        uint16_t* X = (uint16_t*)Cv;
        __syncthreads();
#pragma unroll
        for (int i = 0; i < 3; ++i)
#pragma unroll
            for (int j = 0; j < 2; ++j)
#pragma unroll
                for (int r = 0; r < 4; ++r)
                    yt[(i * 16 + quad * 4 + r) * 132 + wave * 32 + j * 16 + l15] = acc[i][j][r];
        __syncthreads();
        int col = t & 127, half = t >> 7;
        float b = bias[n0 + col];
        float z[36];
#pragma unroll
        for (int j = 0; j < 36; ++j) z[j] = yt[j * 132 + col];
#pragma unroll
        for (int ii = 0; ii < 18; ++ii) {
            int i = half * 18 + ii;
            float zi = z[i] + b;
            float s = 0.f;
#pragma unroll
            for (int j = 0; j < 36; ++j) s += fmaxf(zi + z[j], 0.f);
            X[(size_t)(nb * B_OBJ + i) * D_DIM + n0 + col] = f2bf(s);
        }
    } else {
        float* O = (float*)Cv;
#pragma unroll
        for (int i = 0; i < 3; ++i)
#pragma unroll
            for (int r = 0; r < 4; ++r) {
                int row = i * 16 + quad * 4 + r;
                if (row < B_OBJ) {
#pragma unroll
                    for (int j = 0; j < 2; ++j) {
                        int cc = n0 + wave * 32 + j * 16 + l15;
                        O[(size_t)(nb * B_OBJ + row) * D_DIM + cc] =
                            fmaxf(acc[i][j][r] + bias[cc], 0.f);
                    }
                }
            }
    }
}

extern "C" void kernel_launch(void* const* d_in, const int* in_sizes, int n_in,
                              void* d_out, int out_size, void* d_ws, size_t ws_size,
                              hipStream_t stream) {
    const float* v  = (const float*)d_in[0];
    const float* q  = (const float*)d_in[1];
    const float* W1 = (const float*)d_in[2];
    const float* b1 = (const float*)d_in[3];
    const float* W2 = (const float*)d_in[4];
    const float* b2 = (const float*)d_in[5];
    const float* W3 = (const float*)d_in[6];
    const float* b3 = (const float*)d_in[7];
    float* out = (float*)d_out;

    char* ws = (char*)d_ws;
    uint16_t* W1t   = (uint16_t*)(ws + 0);           // 8 MiB
    uint16_t* W2t   = (uint16_t*)(ws + 8388608);     // 8 MiB
    uint16_t* W3t   = (uint16_t*)(ws + 16777216);    // 4 MiB, dead after qk_gemm
    uint16_t* u     = (uint16_t*)(ws + 16777216);    // 4.5 MiB (overlays dead W3t)
    float*    qpart = (float*)   (ws + 21495808);    // 1 MiB (also pads u over-reads)
    float*    qe    = (float*)   (ws + 22544384);    // 256 KiB
    uint16_t* x     = (uint16_t*)(ws + 22806528);    // 4.5 MiB (ends 27525120)

    transpose_all<<<dim3(32, 80), 256, 0, stream>>>(W1, W2, W3, W1t, W2t, W3t);

    qk_gemm<<<dim3(16, 4), 256, 0, stream>>>(q, W3t, qpart);
    qe_reduce<<<64, 256, 0, stream>>>(qpart, b3, qe);

    make_u<<<(N_BATCH * B_OBJ * D_DIM / 4 + 255) / 256, 256, 0, stream>>>(v, qe, u);

    // GEMM1 + fused pairsum -> x (bf16)
    gemm_batch<<<dim3(16, N_BATCH), 256, 0, stream>>>(u, W1t, b1, x, 0);

    // GEMM2 + bias + relu -> out (f32)
    gemm_batch<<<dim3(16, N_BATCH), 256, 0, stream>>>(x, W2t, b2, out, 1);
}